// Round 10
// baseline (657.182 us; speedup 1.0000x reference)
//
#include <hip/hip_runtime.h>
#include <math.h>

#define T      512
#define NBATCH 512
#define IN_DIM 64
#define H      100
#define KP     208          // padded contraction rows per layer input vector
#define PBYTES 832          // KP*4: byte stride between parity buffers

// tanh(a) = 1 - 2/(exp(2a)+1)  -- overflow-safe at both ends.
__device__ __forceinline__ float fast_tanh(float a) {
    float e = __expf(2.0f * a);
    return 1.0f - 2.0f / (e + 1.0f);
}

// Full-butterfly DPP add: every lane gets the pairwise sum.
#define DPP_ADD(v, ctrl) ((v) + __int_as_float(__builtin_amdgcn_update_dpp( \
        0, __float_as_int(v), (ctrl), 0xF, 0xF, true)))
#define RED8(a) { (a) = DPP_ADD((a), 0xB1);   /* xor 1 (quad_perm) */ \
                  (a) = DPP_ADD((a), 0x4E);   /* xor 2 (quad_perm) */ \
                  (a) = DPP_ADD((a), 0x128);  /* xor 8 (row_ror:8) */ }

// weight element for concatenated row R: rows [0,kA) -> WA, [kA,kA+100) -> WB, else 0
__device__ __forceinline__ float wval(const float* __restrict__ WA,
                                      const float* __restrict__ WB,
                                      int kA, int R, int col) {
    if (R < kA) return WA[R * H + col];
    int rr = R - kA;
    return (rr < H) ? WB[rr * H + col] : 0.f;
}

__device__ __forceinline__ float4 wload4(const float* __restrict__ WA,
                                         const float* __restrict__ WB,
                                         int kA, int R0, int col) {
    return make_float4(wval(WA, WB, kA, R0 + 0, col),
                       wval(WA, WB, kA, R0 + 1, col),
                       wval(WA, WB, kA, R0 + 2, col),
                       wval(WA, WB, kA, R0 + 3, col));
}

// ---------------------------------------------------------------------------
// R7 champion (464us, no spill) + SHORT PATH for pure-L1 waves. L1's real
// K = 164 (x 64 + h1 100) but the padded layout is 208: R7 wasted 21% of L1's
// reads/FMAs on zero rows. Waves 0-2 hold L1 groups 0-23 exclusively, so
// they take a wave-uniform short path: 5 rounds (rows 0-159) + b32 tail
// (row 160+s per lane, covers real rows 160-163) = 6 LDS ops + 84 FMAs
// (vs 7 ops + 104). Waves 3-6 (incl. the mixed wave 3 with L1 group 24)
// run the R7 full path verbatim. Path select wv<3 is wave-uniform -> no
// divergence. Register union unchanged (~118 live, R7-proven no-spill).
// Per half-body: LDS wave-ops 49 -> 46, FMA issue 728 -> 668.
// R9's one-ahead read rotation reverted (measured neutral: compiler already
// schedules the reads; it only added register pressure).
// Everything else R7 verbatim: TWO elems per 1024-thread block (shared
// barriers, 1 block/CU), 8-way K-split (s = lane bits {0,1,3}), 4 cols/group
// (bits {2,4,5}), wave 7 = x-prefetch, all-DPP RED8 reduction.
// ---------------------------------------------------------------------------

#define RNDS(X) X(0) X(1) X(2) X(3) X(4) X(5)

#define WDECL(R) float4 w##R##_0 = {0,0,0,0}, w##R##_1 = {0,0,0,0}, \
                        w##R##_2 = {0,0,0,0}, w##R##_3 = {0,0,0,0};

#define WLOAD(R) { const int r0_ = 32 * (R) + 4 * s;   \
    w##R##_0 = wload4(WA, WB, kA, r0_, j + 0);         \
    w##R##_1 = wload4(WA, WB, kA, r0_, j + 1);         \
    w##R##_2 = wload4(WA, WB, kA, r0_, j + 2);         \
    w##R##_3 = wload4(WA, WB, kA, r0_, j + 3); }

#define FSTEP(R, P) { const float4 v_ = *(const float4*)(rb + (P) + 128 * (R)); \
    a0 = fmaf(v_.x, w##R##_0.x, a0); a1 = fmaf(v_.x, w##R##_1.x, a1);           \
    a2 = fmaf(v_.x, w##R##_2.x, a2); a3 = fmaf(v_.x, w##R##_3.x, a3);           \
    a0 = fmaf(v_.y, w##R##_0.y, a0); a1 = fmaf(v_.y, w##R##_1.y, a1);           \
    a2 = fmaf(v_.y, w##R##_2.y, a2); a3 = fmaf(v_.y, w##R##_3.y, a3);           \
    a0 = fmaf(v_.z, w##R##_0.z, a0); a1 = fmaf(v_.z, w##R##_1.z, a1);           \
    a2 = fmaf(v_.z, w##R##_2.z, a2); a3 = fmaf(v_.z, w##R##_3.z, a3);           \
    a0 = fmaf(v_.w, w##R##_0.w, a0); a1 = fmaf(v_.w, w##R##_1.w, a1);           \
    a2 = fmaf(v_.w, w##R##_2.w, a2); a3 = fmaf(v_.w, w##R##_3.w, a3); }

#define DOT(P, hv) {                                                      \
    float a0 = 0.f, a1 = 0.f, a2 = 0.f, a3 = 0.f;                         \
    FSTEP(0, P) FSTEP(1, P) FSTEP(2, P)                                   \
    FSTEP(3, P) FSTEP(4, P)                                               \
    if (ps) {   /* short path: tail = rows 160..167, one row per lane */  \
        const float vt_ = *(const float*)(tb + (P));                      \
        a0 = fmaf(vt_, wt0.x, a0); a1 = fmaf(vt_, wt1.x, a1);             \
        a2 = fmaf(vt_, wt2.x, a2); a3 = fmaf(vt_, wt3.x, a3);             \
    } else {    /* full path: round 5 + float2 tail rows 192..207 */      \
        FSTEP(5, P)                                                       \
        const float2 v_ = *(const float2*)(tb + (P));                     \
        a0 = fmaf(v_.x, wt0.x, a0); a1 = fmaf(v_.x, wt1.x, a1);           \
        a2 = fmaf(v_.x, wt2.x, a2); a3 = fmaf(v_.x, wt3.x, a3);           \
        a0 = fmaf(v_.y, wt0.y, a0); a1 = fmaf(v_.y, wt1.y, a1);           \
        a2 = fmaf(v_.y, wt2.y, a2); a3 = fmaf(v_.y, wt3.y, a3);           \
    }                                                                     \
    RED8(a0) RED8(a1) RED8(a2) RED8(a3)                                   \
    const float t01_ = (s & 1) ? a1 : a0;                                 \
    const float t23_ = (s & 1) ? a3 : a2;                                 \
    hv = fast_tanh(((s & 2) ? t23_ : t01_) + bj); }

__global__ __launch_bounds__(1024, 4)
void drnn_kernel(const float* __restrict__ x,
                 const float* __restrict__ W1x, const float* __restrict__ W1h,
                 const float* __restrict__ b1,
                 const float* __restrict__ W2x, const float* __restrict__ W2h,
                 const float* __restrict__ b2,
                 const float* __restrict__ Wo,  const float* __restrict__ bo,
                 float* __restrict__ out)
{
    // per elem: in1 = [x_t(64) | h1(100) | pad->208]; in2 = [h1(100) | h2(100) | pad]
    __shared__ __align__(16) float in1[2][2][KP];   // [elem][parity][KP]
    __shared__ __align__(16) float in2[2][2][KP];

    const int tid  = threadIdx.x;
    const int e    = tid >> 9;                   // which batch element (0/1)
    const int t    = tid & 511;                  // thread id within the half
    const int b    = 2 * blockIdx.x + e;
    const int lane = t & 63;
    const int wv   = t >> 6;
    const int s    = (lane & 3) | ((lane >> 1) & 4);        // K-slice: lane bits {0,1,3}
    const int gw   = ((lane >> 2) & 1) | ((lane >> 3) & 6); // group-in-wave: bits {2,4,5}
    const int gg   = wv * 8 + gw;                           // global group 0..63
    const bool active = (gg < 50);               // 25 L1 + 25 L2 groups
    const bool isL1   = (gg < 25);
    const bool isXL   = (wv == 7);               // x-prefetch wave
    const bool ps     = (wv < 3);                // short path: pure-L1 waves (K=164)

    const float* __restrict__ xrow = x + (size_t)b * T * IN_DIM;

    // ---- zero-init this elem's LDS (pads stay 0; h(-1)=0; h2(-1) stays 0) ----
    for (int k = t; k < 2 * KP; k += 512) {
        (&in1[e][0][0])[k] = 0.f;
        (&in2[e][0][0])[k] = 0.f;
    }
    if (t < IN_DIM) in1[e][0][t] = xrow[t];      // x(0)

    const float* __restrict__ WA = isL1 ? W1x : W2x;
    const float* __restrict__ WB = isL1 ? W1h : W2h;
    const int kA = isL1 ? IN_DIM : H;            // rows [0,kA)->WA, [kA,kA+100)->WB
    const int gl = isL1 ? gg : gg - 25;
    const int nl = (gl >= 0 && gl < 25) ? gl : 0;
    const int j  = 4 * nl;                       // col base (exact: 4*24+3 = 99 max)
    const int n  = j + (s & 3);                  // col this lane finalizes
    const float bj = active ? (isL1 ? b1 : b2)[n] : 0.f;

    // ---- weight registers: rounds 0-4 always; round 5 + tail per path ----
    RNDS(WDECL)
    float2 wt0 = {0,0}, wt1 = {0,0}, wt2 = {0,0}, wt3 = {0,0};
    if (active) {
        WLOAD(0) WLOAD(1) WLOAD(2) WLOAD(3) WLOAD(4)
        if (ps) {                                // short tail: one row 160+s per lane
            const int rt = 160 + s;
            wt0.x = wval(WA,WB,kA,rt,j+0); wt1.x = wval(WA,WB,kA,rt,j+1);
            wt2.x = wval(WA,WB,kA,rt,j+2); wt3.x = wval(WA,WB,kA,rt,j+3);
        } else {                                 // full: round 5 + rows 192+2s,193+2s
            WLOAD(5)
            const int rt = 192 + 2 * s;
            wt0 = make_float2(wval(WA,WB,kA,rt,j+0), wval(WA,WB,kA,rt+1,j+0));
            wt1 = make_float2(wval(WA,WB,kA,rt,j+1), wval(WA,WB,kA,rt+1,j+1));
            wt2 = make_float2(wval(WA,WB,kA,rt,j+2), wval(WA,WB,kA,rt+1,j+2));
            wt3 = make_float2(wval(WA,WB,kA,rt,j+3), wval(WA,WB,kA,rt+1,j+3));
        }
    }

    // ---- per-lane LDS pointers; odd parity reached via +PBYTES immediate ----
    const char* lb = (const char*)(isL1 ? &in1[e][0][0] : &in2[e][0][0]);
    const char* rb = lb + 16 * s;                // round R at byte offset P + 128*R
    const char* tb = lb + (ps ? 640 + 4 * s      // short tail float 160+s
                              : 768 + 8 * s);    // full tail float2 rows 192+2s

    // parity-0 store slot; dup pair (s, s+4) carries L1's two destinations
    char* st;
    if (isL1) st = (char*)((s < 4) ? &in1[e][0][64 + n] : &in2[e][0][n]);
    else      st = (char*)&in2[e][0][100 + n];
    const bool dost = active && (isL1 || s < 4);

    // ---- x register pipeline (wave 7 of this half), two steps ahead ----
    char* xw = (char*)&in1[e][0][lane];
    float xr0 = 0.f, xr1 = 0.f;
    if (isXL) {
        xr0 = xrow[1 * IN_DIM + lane];           // x(1)
        xr1 = xrow[2 * IN_DIM + lane];           // x(2)
    }

    __syncthreads();

    // Body i: L1 computes h1(i); L2 computes h2(i-1). Wave 7 stages x(i+1).
    #pragma unroll 1
    for (int i = 0; i < T; i += 2) {
        // ---- even body: read parity 0, write parity 1 ----
        if (active) {
            float hv; DOT(0, hv)
            if (dost && (isL1 || i > 0)) *(float*)(st + PBYTES) = hv; // skip bogus h2(-1)
        } else if (isXL) {
            *(float*)(xw + PBYTES) = xr0;        // x(i+1)
            xr0 = xr1;
            if (i + 3 < T) xr1 = xrow[(size_t)(i + 3) * IN_DIM + lane];
        }
        __syncthreads();
        // ---- odd body: read parity 1, write parity 0 ----
        if (active) {
            float hv; DOT(PBYTES, hv)
            if (dost) *(float*)st = hv;
        } else if (isXL) {
            *(float*)xw = xr0;                   // x(i+2)
            xr0 = xr1;
            if (i + 4 < T) xr1 = xrow[(size_t)(i + 4) * IN_DIM + lane];
        }
        __syncthreads();
    }

    // ---- tail body (parity 0): only L2, computes h2(T-1) ----
    if (active && !isL1) {
        float hv; DOT(0, hv)                     // in2[e][0]: h1(T-1) + h2(T-2)
        if (dost) *(float*)(st + PBYTES) = hv;   // -> in2[e][1][100..]
    }
    __syncthreads();

    // ---- epilogue: h1(T-1) in in1[e][0][64..], h2(T-1) in in2[e][1][100..] ----
    if (t < H)
        out[NBATCH + (size_t)b * H + t] = in1[e][0][64 + t];
    if (t < H)
        out[NBATCH + (size_t)NBATCH * H + (size_t)b * H + t] = in2[e][1][100 + t];

    // out[b] = h2_T . Wo + bo  (one wave per half does the shuffle reduction)
    if (t < 64) {
        float v = in2[e][1][100 + t] * Wo[t];
        if (t + 64 < H) v += in2[e][1][100 + 64 + t] * Wo[t + 64];
        #pragma unroll
        for (int off = 32; off >= 1; off >>= 1) v += __shfl_down(v, off);
        if (t == 0) out[b] = v + bo[0];
    }
}

extern "C" void kernel_launch(void* const* d_in, const int* in_sizes, int n_in,
                              void* d_out, int out_size, void* d_ws, size_t ws_size,
                              hipStream_t stream) {
    const float* x   = (const float*)d_in[0];
    const float* W1x = (const float*)d_in[1];
    const float* W1h = (const float*)d_in[2];
    const float* b1  = (const float*)d_in[3];
    const float* W2x = (const float*)d_in[4];
    const float* W2h = (const float*)d_in[5];
    const float* b2  = (const float*)d_in[6];
    const float* Wo  = (const float*)d_in[7];
    const float* bo  = (const float*)d_in[8];
    float* out = (float*)d_out;

    drnn_kernel<<<NBATCH / 2, 1024, 0, stream>>>(x, W1x, W1h, b1, W2x, W2h, b2,
                                                 Wo, bo, out);
}

// Round 11
// 499.717 us; speedup vs baseline: 1.3151x; 1.3151x over previous
//
#include <hip/hip_runtime.h>
#include <math.h>

#define T      512
#define NBATCH 512
#define IN_DIM 64
#define H      100
#define KP     208          // padded contraction rows per layer input vector
#define PBYTES 832          // KP*4: byte stride between parity buffers

// tanh(a) = 1 - 2/(exp(2a)+1)  -- overflow-safe at both ends.
__device__ __forceinline__ float fast_tanh(float a) {
    float e = __expf(2.0f * a);
    return 1.0f - 2.0f / (e + 1.0f);
}

// Full-butterfly DPP add: every lane gets the pairwise sum.
#define DPP_ADD(v, ctrl) ((v) + __int_as_float(__builtin_amdgcn_update_dpp( \
        0, __float_as_int(v), (ctrl), 0xF, 0xF, true)))
#define RED8(a) { (a) = DPP_ADD((a), 0xB1);   /* xor 1 (quad_perm) */ \
                  (a) = DPP_ADD((a), 0x4E);   /* xor 2 (quad_perm) */ \
                  (a) = DPP_ADD((a), 0x128);  /* xor 8 (row_ror:8) */ }

// weight element for concatenated row R: rows [0,kA) -> WA, [kA,kA+100) -> WB, else 0
__device__ __forceinline__ float wval(const float* __restrict__ WA,
                                      const float* __restrict__ WB,
                                      int kA, int R, int col) {
    if (R < kA) return WA[R * H + col];
    int rr = R - kA;
    return (rr < H) ? WB[rr * H + col] : 0.f;
}

__device__ __forceinline__ float4 wload4(const float* __restrict__ WA,
                                         const float* __restrict__ WB,
                                         int kA, int R0, int col) {
    return make_float4(wval(WA, WB, kA, R0 + 0, col),
                       wval(WA, WB, kA, R0 + 1, col),
                       wval(WA, WB, kA, R0 + 2, col),
                       wval(WA, WB, kA, R0 + 3, col));
}

// ---------------------------------------------------------------------------
// R7 CHAMPION, restored byte-for-byte (464us dispatches, WRITE_SIZE 408KB =
// no spill). TWO batch elements per 1024-thread block; each 512-thread half:
// 8-way K-split (s = lane bits {0,1,3}), 4 cols/group (g = lane bits
// {2,4,5}), 25 L1 + 25 L2 groups over waves 0-6 (L2 one timestep behind),
// wave 7 = x-prefetch. Per thread: 104 weight floats (24 float4 + 4 float2
// tails), 104 fmaf, 6 ds_read_b128 + 1 b64 per DOT, all-DPP RED8 reduction
// (zero LDS-pipe traffic), live set ~118 < the ~126 spill cliff.
// Shared barriers amortize per-timestep overhead over 2 elements; grid
// = 256 = exactly 1 block/CU (16 waves, 4/SIMD).
// Session post-mortems (R2-R6, R8-R10): every structural change to the DOT
// body or register union tipped the cliff (WRITE_SIZE 6-14MB scratch) or
// paid AGPR-copy tax (asm pk_fma). C=8 dead (4 attempts), dual-path DOT
// dead (R10), explicit read pipelining neutral (R9, compiler already does
// it). This config is the measured optimum of the design space.
// ---------------------------------------------------------------------------

#define RNDS(X) X(0) X(1) X(2) X(3) X(4) X(5)

#define WDECL(R) float4 w##R##_0 = {0,0,0,0}, w##R##_1 = {0,0,0,0}, \
                        w##R##_2 = {0,0,0,0}, w##R##_3 = {0,0,0,0};

#define WLOAD(R) { const int r0_ = 32 * (R) + 4 * s;   \
    w##R##_0 = wload4(WA, WB, kA, r0_, j + 0);         \
    w##R##_1 = wload4(WA, WB, kA, r0_, j + 1);         \
    w##R##_2 = wload4(WA, WB, kA, r0_, j + 2);         \
    w##R##_3 = wload4(WA, WB, kA, r0_, j + 3); }

#define FSTEP(R, P) { const float4 v_ = *(const float4*)(rb + (P) + 128 * (R)); \
    a0 = fmaf(v_.x, w##R##_0.x, a0); a1 = fmaf(v_.x, w##R##_1.x, a1);           \
    a2 = fmaf(v_.x, w##R##_2.x, a2); a3 = fmaf(v_.x, w##R##_3.x, a3);           \
    a0 = fmaf(v_.y, w##R##_0.y, a0); a1 = fmaf(v_.y, w##R##_1.y, a1);           \
    a2 = fmaf(v_.y, w##R##_2.y, a2); a3 = fmaf(v_.y, w##R##_3.y, a3);           \
    a0 = fmaf(v_.z, w##R##_0.z, a0); a1 = fmaf(v_.z, w##R##_1.z, a1);           \
    a2 = fmaf(v_.z, w##R##_2.z, a2); a3 = fmaf(v_.z, w##R##_3.z, a3);           \
    a0 = fmaf(v_.w, w##R##_0.w, a0); a1 = fmaf(v_.w, w##R##_1.w, a1);           \
    a2 = fmaf(v_.w, w##R##_2.w, a2); a3 = fmaf(v_.w, w##R##_3.w, a3); }

#define DOT(P, hv) {                                                      \
    float a0 = 0.f, a1 = 0.f, a2 = 0.f, a3 = 0.f;                         \
    FSTEP(0, P) FSTEP(1, P) FSTEP(2, P)                                   \
    FSTEP(3, P) FSTEP(4, P) FSTEP(5, P)                                   \
    { const float2 v_ = *(const float2*)(tb + (P));                       \
      a0 = fmaf(v_.x, wt0.x, a0); a1 = fmaf(v_.x, wt1.x, a1);             \
      a2 = fmaf(v_.x, wt2.x, a2); a3 = fmaf(v_.x, wt3.x, a3);             \
      a0 = fmaf(v_.y, wt0.y, a0); a1 = fmaf(v_.y, wt1.y, a1);             \
      a2 = fmaf(v_.y, wt2.y, a2); a3 = fmaf(v_.y, wt3.y, a3); }           \
    RED8(a0) RED8(a1) RED8(a2) RED8(a3)                                   \
    const float t01_ = (s & 1) ? a1 : a0;                                 \
    const float t23_ = (s & 1) ? a3 : a2;                                 \
    hv = fast_tanh(((s & 2) ? t23_ : t01_) + bj); }

__global__ __launch_bounds__(1024, 4)
void drnn_kernel(const float* __restrict__ x,
                 const float* __restrict__ W1x, const float* __restrict__ W1h,
                 const float* __restrict__ b1,
                 const float* __restrict__ W2x, const float* __restrict__ W2h,
                 const float* __restrict__ b2,
                 const float* __restrict__ Wo,  const float* __restrict__ bo,
                 float* __restrict__ out)
{
    // per elem: in1 = [x_t(64) | h1(100) | pad->208]; in2 = [h1(100) | h2(100) | pad]
    __shared__ __align__(16) float in1[2][2][KP];   // [elem][parity][KP]
    __shared__ __align__(16) float in2[2][2][KP];

    const int tid  = threadIdx.x;
    const int e    = tid >> 9;                   // which batch element (0/1)
    const int t    = tid & 511;                  // thread id within the half
    const int b    = 2 * blockIdx.x + e;
    const int lane = t & 63;
    const int wv   = t >> 6;
    const int s    = (lane & 3) | ((lane >> 1) & 4);        // K-slice: lane bits {0,1,3}
    const int gw   = ((lane >> 2) & 1) | ((lane >> 3) & 6); // group-in-wave: bits {2,4,5}
    const int gg   = wv * 8 + gw;                           // global group 0..63
    const bool active = (gg < 50);               // 25 L1 + 25 L2 groups
    const bool isL1   = (gg < 25);
    const bool isXL   = (wv == 7);               // x-prefetch wave

    const float* __restrict__ xrow = x + (size_t)b * T * IN_DIM;

    // ---- zero-init this elem's LDS (pads stay 0; h(-1)=0; h2(-1) stays 0) ----
    for (int k = t; k < 2 * KP; k += 512) {
        (&in1[e][0][0])[k] = 0.f;
        (&in2[e][0][0])[k] = 0.f;
    }
    if (t < IN_DIM) in1[e][0][t] = xrow[t];      // x(0)

    const float* __restrict__ WA = isL1 ? W1x : W2x;
    const float* __restrict__ WB = isL1 ? W1h : W2h;
    const int kA = isL1 ? IN_DIM : H;            // rows [0,kA)->WA, [kA,kA+100)->WB
    const int gl = isL1 ? gg : gg - 25;
    const int nl = (gl >= 0 && gl < 25) ? gl : 0;
    const int j  = 4 * nl;                       // col base (exact: 4*24+3 = 99 max)
    const int n  = j + (s & 3);                  // col this lane finalizes
    const float bj = active ? (isL1 ? b1 : b2)[n] : 0.f;

    // ---- 104 named weight floats: 24 float4 + 4 float2 (tail rows 192..207) ----
    RNDS(WDECL)
    float2 wt0 = {0,0}, wt1 = {0,0}, wt2 = {0,0}, wt3 = {0,0};
    if (active) {
        RNDS(WLOAD)
        const int rt = 192 + 2 * s;
        wt0 = make_float2(wval(WA,WB,kA,rt,j+0), wval(WA,WB,kA,rt+1,j+0));
        wt1 = make_float2(wval(WA,WB,kA,rt,j+1), wval(WA,WB,kA,rt+1,j+1));
        wt2 = make_float2(wval(WA,WB,kA,rt,j+2), wval(WA,WB,kA,rt+1,j+2));
        wt3 = make_float2(wval(WA,WB,kA,rt,j+3), wval(WA,WB,kA,rt+1,j+3));
    }

    // ---- per-lane LDS pointers; odd parity reached via +PBYTES immediate ----
    const char* lb = (const char*)(isL1 ? &in1[e][0][0] : &in2[e][0][0]);
    const char* rb = lb + 16 * s;                // round R at byte offset P + 128*R
    const char* tb = lb + 768 + 8 * s;           // float2 tail rows 192+2s

    // parity-0 store slot; dup pair (s, s+4) carries L1's two destinations
    char* st;
    if (isL1) st = (char*)((s < 4) ? &in1[e][0][64 + n] : &in2[e][0][n]);
    else      st = (char*)&in2[e][0][100 + n];
    const bool dost = active && (isL1 || s < 4);

    // ---- x register pipeline (wave 7 of this half), two steps ahead ----
    char* xw = (char*)&in1[e][0][lane];
    float xr0 = 0.f, xr1 = 0.f;
    if (isXL) {
        xr0 = xrow[1 * IN_DIM + lane];           // x(1)
        xr1 = xrow[2 * IN_DIM + lane];           // x(2)
    }

    __syncthreads();

    // Body i: L1 computes h1(i); L2 computes h2(i-1). Wave 7 stages x(i+1).
    #pragma unroll 1
    for (int i = 0; i < T; i += 2) {
        // ---- even body: read parity 0, write parity 1 ----
        if (active) {
            float hv; DOT(0, hv)
            if (dost && (isL1 || i > 0)) *(float*)(st + PBYTES) = hv; // skip bogus h2(-1)
        } else if (isXL) {
            *(float*)(xw + PBYTES) = xr0;        // x(i+1)
            xr0 = xr1;
            if (i + 3 < T) xr1 = xrow[(size_t)(i + 3) * IN_DIM + lane];
        }
        __syncthreads();
        // ---- odd body: read parity 1, write parity 0 ----
        if (active) {
            float hv; DOT(PBYTES, hv)
            if (dost) *(float*)st = hv;
        } else if (isXL) {
            *(float*)xw = xr0;                   // x(i+2)
            xr0 = xr1;
            if (i + 4 < T) xr1 = xrow[(size_t)(i + 4) * IN_DIM + lane];
        }
        __syncthreads();
    }

    // ---- tail body (parity 0): only L2, computes h2(T-1) ----
    if (active && !isL1) {
        float hv; DOT(0, hv)                     // in2[e][0]: h1(T-1) + h2(T-2)
        if (dost) *(float*)(st + PBYTES) = hv;   // -> in2[e][1][100..]
    }
    __syncthreads();

    // ---- epilogue: h1(T-1) in in1[e][0][64..], h2(T-1) in in2[e][1][100..] ----
    if (t < H)
        out[NBATCH + (size_t)b * H + t] = in1[e][0][64 + t];
    if (t < H)
        out[NBATCH + (size_t)NBATCH * H + (size_t)b * H + t] = in2[e][1][100 + t];

    // out[b] = h2_T . Wo + bo  (one wave per half does the shuffle reduction)
    if (t < 64) {
        float v = in2[e][1][100 + t] * Wo[t];
        if (t + 64 < H) v += in2[e][1][100 + 64 + t] * Wo[t + 64];
        #pragma unroll
        for (int off = 32; off >= 1; off >>= 1) v += __shfl_down(v, off);
        if (t == 0) out[b] = v + bo[0];
    }
}

extern "C" void kernel_launch(void* const* d_in, const int* in_sizes, int n_in,
                              void* d_out, int out_size, void* d_ws, size_t ws_size,
                              hipStream_t stream) {
    const float* x   = (const float*)d_in[0];
    const float* W1x = (const float*)d_in[1];
    const float* W1h = (const float*)d_in[2];
    const float* b1  = (const float*)d_in[3];
    const float* W2x = (const float*)d_in[4];
    const float* W2h = (const float*)d_in[5];
    const float* b2  = (const float*)d_in[6];
    const float* Wo  = (const float*)d_in[7];
    const float* bo  = (const float*)d_in[8];
    float* out = (float*)d_out;

    drnn_kernel<<<NBATCH / 2, 1024, 0, stream>>>(x, W1x, W1h, b1, W2x, W2h, b2,
                                                 Wo, bo, out);
}